// Round 3
// baseline (383.568 us; speedup 1.0000x reference)
//
#include <hip/hip_runtime.h>
#include <stdint.h>

// BinarizeLinear inference: out = sign(X) @ sign(W) + bias
// X: [8192, 4096] f32, W: [4096, 4096] f32 (in_features major), bias: [4096] f32
// Strategy: XNOR-popcount GEMM. Pack sign bits into uint64 words (64 words per
// 4096-length row), dot = 4096 - 2*popcount(xbits ^ wbits). Exact integer math.

#define N_ROWS 8192
#define K_DIM  4096
#define O_DIM  4096
#define KW     64        // uint64 words per K-row (4096/64)

// ---------------- pack X: one wave per row, ballot packs 64 signs/step ------
__global__ __launch_bounds__(256) void pack_x_kernel(
        const float* __restrict__ X, uint64_t* __restrict__ Xb) {
    int wave = (int)((blockIdx.x * blockDim.x + threadIdx.x) >> 6);
    int lane = threadIdx.x & 63;
    if (wave >= N_ROWS) return;
    const float* xr = X + (size_t)wave * K_DIM;
    uint64_t* xbr = Xb + (size_t)wave * KW;
    #pragma unroll 4
    for (int w = 0; w < KW; ++w) {
        float v = xr[w * 64 + lane];
        unsigned long long m = __ballot(v > 0.0f);
        if (lane == 0) xbr[w] = (uint64_t)m;
    }
}

// ---------------- pack W: thread per output column, builds one word ---------
// grid: (o_chunks=16) x (widx=64) flattened; 256 threads
__global__ __launch_bounds__(256) void pack_w_kernel(
        const float* __restrict__ W, uint64_t* __restrict__ Wb) {
    int oc = blockIdx.x & 15;
    int w  = blockIdx.x >> 4;
    int o  = oc * 256 + threadIdx.x;
    const float* wp = W + (size_t)(w * 64) * O_DIM + o;
    uint64_t word = 0;
    #pragma unroll 8
    for (int p = 0; p < 64; ++p) {
        float v = wp[(size_t)p * O_DIM];     // coalesced across threads (consecutive o)
        word |= (uint64_t)(v > 0.0f) << p;
    }
    Wb[(size_t)o * KW + w] = word;
}

// ---------------- XNOR GEMM: 128x128 tile, 8x8/thread, LDS-chunked K --------
#define BM 128
#define BN 128
#define KB 16    // words per K-chunk (16 * 64 = 1024 k per chunk)
#define TM 8
#define TN 8

// XOR swizzle: spreads groups of 8 rows across 16B slots -> <=2-way conflicts
__device__ __forceinline__ int swz(int row, int k) {
    return ((row * KB + k) << 3) ^ (((row >> 3) & 7) << 4);
}

__global__ __launch_bounds__(256, 2) void xnor_gemm_kernel(
        const uint64_t* __restrict__ Xb, const uint64_t* __restrict__ Wb,
        const float* __restrict__ bias, float* __restrict__ out) {
    __shared__ uint8_t lds[2 * BM * KB * 8];   // 32 KiB: X panel then W panel
    uint8_t* xs = lds;
    uint8_t* ws = lds + BM * KB * 8;

    const int tid    = threadIdx.x;
    const int tile_m = blockIdx.x >> 5;    // 64 M-tiles
    const int tile_n = blockIdx.x & 31;    // 32 N-tiles
    const int brow   = tile_m * BM;
    const int bcol   = tile_n * BN;
    const int tx     = tid & 15;           // 16 col-groups
    const int ty     = tid >> 4;           // 16 row-groups

    uint32_t acc[TM][TN];
    #pragma unroll
    for (int r = 0; r < TM; ++r)
        #pragma unroll
        for (int c = 0; c < TN; ++c) acc[r][c] = 0;

    for (int kc = 0; kc < KW / KB; ++kc) {
        __syncthreads();   // protect LDS from previous-iteration readers
        #pragma unroll
        for (int i = 0; i < (BM * KB) / 256; ++i) {   // 8 words per thread
            int idx = tid + i * 256;
            int row = idx >> 4;   // /KB
            int k   = idx & 15;
            *(uint64_t*)(xs + swz(row, k)) =
                Xb[(size_t)(brow + row) * KW + kc * KB + k];
            *(uint64_t*)(ws + swz(row, k)) =
                Wb[(size_t)(bcol + row) * KW + kc * KB + k];
        }
        __syncthreads();

        #pragma unroll 4
        for (int k = 0; k < KB; ++k) {
            uint64_t xf[TM], wf[TN];
            #pragma unroll
            for (int r = 0; r < TM; ++r)
                xf[r] = *(const uint64_t*)(xs + swz(ty * TM + r, k));
            #pragma unroll
            for (int c = 0; c < TN; ++c)
                wf[c] = *(const uint64_t*)(ws + swz(tx * TN + c, k));
            #pragma unroll
            for (int r = 0; r < TM; ++r)
                #pragma unroll
                for (int c = 0; c < TN; ++c)
                    acc[r][c] += (uint32_t)__builtin_popcountll(xf[r] ^ wf[c]);
        }
    }

    // epilogue: dot = K_DIM - 2*popc_total; add bias; float4 stores
    float bv[TN];
    #pragma unroll
    for (int c = 0; c < TN; ++c) bv[c] = bias[bcol + tx * TN + c];

    #pragma unroll
    for (int r = 0; r < TM; ++r) {
        float vals[TN];
        #pragma unroll
        for (int c = 0; c < TN; ++c)
            vals[c] = (float)(K_DIM - 2 * (int)acc[r][c]) + bv[c];
        float4* op = (float4*)(out + (size_t)(brow + ty * TM + r) * O_DIM
                               + bcol + tx * TN);
        op[0] = make_float4(vals[0], vals[1], vals[2], vals[3]);
        op[1] = make_float4(vals[4], vals[5], vals[6], vals[7]);
    }
}

extern "C" void kernel_launch(void* const* d_in, const int* in_sizes, int n_in,
                              void* d_out, int out_size, void* d_ws, size_t ws_size,
                              hipStream_t stream) {
    const float* X    = (const float*)d_in[0];   // [8192, 4096]
    const float* W    = (const float*)d_in[1];   // [4096, 4096]
    const float* bias = (const float*)d_in[2];   // [4096]
    float* out        = (float*)d_out;           // [8192, 4096]

    uint64_t* Xb = (uint64_t*)d_ws;                              // 4 MiB
    uint64_t* Wb = (uint64_t*)((uint8_t*)d_ws + (size_t)N_ROWS * KW * 8); // 2 MiB

    // pack X: 8192 waves (one per row), 4 waves/block
    pack_x_kernel<<<N_ROWS / 4, 256, 0, stream>>>(X, Xb);
    // pack W: 16 o-chunks x 64 words
    pack_w_kernel<<<16 * 64, 256, 0, stream>>>(W, Wb);
    // GEMM: 64 x 32 tiles of 128x128
    xnor_gemm_kernel<<<(N_ROWS / BM) * (O_DIM / BN), 256, 0, stream>>>(
        Xb, Wb, bias, out);
}